// Round 17
// baseline (2318.114 us; speedup 1.0000x reference)
//
#include <hip/hip_runtime.h>
#include <stdint.h>

#define TSEQ  784
#define BATCH 256
#define HID   256
#define DNS   1024
#define NCLS  10
#define NGRP  16   // groups (16 batch rows each)
#define NSLC  8    // slices (32 units x 4 gates = 128 gate-cols each)

typedef __attribute__((ext_vector_type(8))) short bf16x8_t;
typedef __attribute__((ext_vector_type(4))) float f32x4_t;

__device__ __forceinline__ float sigmoidf_(float x) { return 1.0f / (1.0f + __expf(-x)); }
__device__ __forceinline__ float tanhf_(float x) {
    float ax = fabsf(x);
    float e  = __expf(2.0f * ax);
    float r  = 1.0f - 2.0f / (e + 1.0f);
    return copysignf(r, x);
}
__device__ __forceinline__ uint32_t bf16rne(float f) {
    uint32_t u = __float_as_uint(f);
    return (u + 0x7FFFu + ((u >> 16) & 1u)) >> 16;
}
__device__ __forceinline__ float bf16tof(uint32_t h) { return __uint_as_float(h << 16); }

// 128 blocks = 16 groups x 8 slices, 256 threads (4 waves). Round-15 compute
// (B-frag hoist+pin, best: 2127 us) with the end-of-step chain de-serialized:
//  - 32 PER-WAVE tags per group (one 128 B line; distinct words -> no RMW
//    contention, unlike r14's shared counter);
//  - each wave drains ITS OWN h-stores (vmcnt is per-wave) then lane0 tags;
//  - ALL waves poll the 32-tag line (one 128 B request/wave) -> no join
//    barrier, no final barrier: 2 barriers/step.
// Race-free: a wave stages hA for step t only after ALL 32 tags >= t, and a
// wave tags t only after its eltwise of t-1 (hence after its hA/gateL reads).
__global__ __launch_bounds__(256, 1)
void lstm_mfma(const float* __restrict__ X,
               const float* __restrict__ W_lstm,
               const float* __restrict__ b_lstm,
               uint32_t* __restrict__ hx,      // 2 bufs * 16 g * 8 s * 512 dwords
               uint32_t* __restrict__ tags)    // 16 groups * 32 per-wave tags
{
    __shared__ uint32_t WtU[32768];           // 128 KB weights bf16 hi/lo (frag source)
    __shared__ uint32_t hA[4096];             // 16 KB h_t (hi/lo), A-frag order, swizzled
    __shared__ float    gateL[4 * 32 * 17];   // 8.5 KB gates [q][col][row+pad]

    const int tid  = threadIdx.x;
    const int lane = tid & 63;
    const int wid  = tid >> 6;    // 0..3 == gate q owned by this wave
    const int cidx = lane & 15;   // B col / A row within tile
    const int kh   = lane >> 4;   // 0..3 k-subgroup

    const int bid = blockIdx.x;
    const int s   = bid >> 4;     // slice 0..7
    const int g   = bid & 15;     // group 0..15

    // ---- one-time: stage Wh slice into LDS as bf16 hi/lo, chunk-XOR-swizzled ----
    for (int idx = tid; idx < 8 * 16 * 128; idx += 256) {
        const int n  = idx >> 11;          // n-tile 0..7
        const int c  = (idx >> 7) & 15;    // col within tile
        const int dw = idx & 127;          // k-pair index
        const int k0 = dw * 2;
        const int col = (n >> 1) * 256 + s * 32 + (n & 1) * 16 + c;
        const float w0 = W_lstm[(1 + k0) * 1024 + col];
        const float w1 = W_lstm[(2 + k0) * 1024 + col];
        const uint32_t h0 = bf16rne(w0), h1 = bf16rne(w1);
        const uint32_t l0 = bf16rne(w0 - bf16tof(h0));
        const uint32_t l1 = bf16rne(w1 - bf16tof(h1));
        const int kc = dw >> 2, rem = dw & 3;
        const int dwp = ((kc ^ (c & 7)) << 2) | rem;
        const int o = (n * 16 + c) * 128 + dwp;
        WtU[o]         = h0 | (h1 << 16);
        WtU[16384 + o] = l0 | (l1 << 16);
    }

    // eltwise mapping: thread -> (row er, unit eu); cells (er,eu),(er,eu+16)
    const int er = tid >> 4;
    const int eu = tid & 15;
    float wx0[4], wx1[4], bb0[4], bb1[4];
    #pragma unroll
    for (int q = 0; q < 4; ++q) {
        const int c0 = q * 256 + s * 32 + eu;
        wx0[q] = W_lstm[c0];      wx1[q] = W_lstm[c0 + 16];
        bb0[q] = b_lstm[c0];      bb1[q] = b_lstm[c0 + 16];
    }
    const float* xrow = X + (g * 16 + er) * TSEQ;
    float cc0 = 0.0f, cc1 = 0.0f;

    const int key = (cidx + (cidx >> 2)) & 3;   // hA read swizzle key
    const int kq  = (kh ^ key) << 2;

    __syncthreads();

    // ---- hoist this wave's B-fragments into registers (32 x bf16x8) ----
    bf16x8_t Bh0[8], Bl0[8], Bh1[8], Bl1[8];
    #pragma unroll
    for (int kt = 0; kt < 8; ++kt) {
        const int kc  = kt * 4 + kh;
        const int ob0 = ((wid * 2) * 16 + cidx) * 128 + ((kc ^ (cidx & 7)) << 2);
        const int ob1 = ((wid * 2 + 1) * 16 + cidx) * 128 + ((kc ^ (cidx & 7)) << 2);
        Bh0[kt] = *reinterpret_cast<const bf16x8_t*>(&WtU[ob0]);
        Bl0[kt] = *reinterpret_cast<const bf16x8_t*>(&WtU[16384 + ob0]);
        Bh1[kt] = *reinterpret_cast<const bf16x8_t*>(&WtU[ob1]);
        Bl1[kt] = *reinterpret_cast<const bf16x8_t*>(&WtU[16384 + ob1]);
    }

    for (int t = 0; t < TSEQ; ++t) {
        // PIN: loop-carried residency hint for the B-fragments (r15 win: kept).
        #pragma unroll
        for (int kt = 0; kt < 8; kt += 4) {
            asm volatile("" : "+v"(Bh0[kt]), "+v"(Bh0[kt+1]), "+v"(Bh0[kt+2]), "+v"(Bh0[kt+3]),
                              "+v"(Bl0[kt]), "+v"(Bl0[kt+1]), "+v"(Bl0[kt+2]), "+v"(Bl0[kt+3]));
            asm volatile("" : "+v"(Bh1[kt]), "+v"(Bh1[kt+1]), "+v"(Bh1[kt+2]), "+v"(Bh1[kt+3]),
                              "+v"(Bl1[kt]), "+v"(Bl1[kt+1]), "+v"(Bl1[kt+2]), "+v"(Bl1[kt+3]));
        }

        // ---- ALL waves poll the 32 per-wave tags >= t (one 128 B request) ----
        if (t > 0) {
            const uint32_t tt = (uint32_t)t;
            int guard = 1 << 22;
            bool ok;
            do {
                uint32_t v = tt;
                if (lane < 32) {
                    v = __hip_atomic_load(&tags[g * 32 + lane],
                                          __ATOMIC_RELAXED, __HIP_MEMORY_SCOPE_AGENT);
                }
                ok = __all(v >= tt);
            } while (!ok && --guard);
        }
        asm volatile("" ::: "memory");   // stage loads cannot hoist above poll

        // ---- stage h_t (hi+lo, all 8 chunks = 16 KB) into LDS, coalesced u64 ----
        {
            const int bufr = t & 1;
            const unsigned long long* src =
                (const unsigned long long*)hx + (size_t)(bufr * NGRP + g) * 2048;
            unsigned long long v[8];
            #pragma unroll
            for (int j = 0; j < 8; ++j) {
                v[j] = __hip_atomic_load(&src[j * 256 + tid],
                                         __ATOMIC_RELAXED, __HIP_MEMORY_SCOPE_AGENT);
            }
            #pragma unroll
            for (int j = 0; j < 8; ++j) {
                const int m   = j * 256 + tid;      // u64 index; dword n = 2m
                const int kt  = m >> 8;
                const int lvl = (m >> 7) & 1;
                const int ci  = (m & 127) >> 3;
                const int ko  = (m & 7) * 2;        // even koff
                const int khj = ko >> 2, dp = ko & 3;
                const int kyj = (ci + (ci >> 2)) & 3;
                const int dst = kt * 512 + lvl * 256 + ci * 16 + ((khj ^ kyj) << 2) + dp;
                *(unsigned long long*)&hA[dst] = v[j];
            }
        }
        __syncthreads();

        // ---- GEMM: 3-term split over 8 k-tiles, B from registers/pin ----
        f32x4_t acc0 = {0.f, 0.f, 0.f, 0.f}, acc1 = acc0;
        #pragma unroll
        for (int kt = 0; kt < 8; ++kt) {
            bf16x8_t av_h = *reinterpret_cast<const bf16x8_t*>(&hA[kt * 512 + cidx * 16 + kq]);
            bf16x8_t av_l = *reinterpret_cast<const bf16x8_t*>(&hA[kt * 512 + 256 + cidx * 16 + kq]);
            acc0 = __builtin_amdgcn_mfma_f32_16x16x32_bf16(av_h, Bh0[kt], acc0, 0, 0, 0);
            acc0 = __builtin_amdgcn_mfma_f32_16x16x32_bf16(av_h, Bl0[kt], acc0, 0, 0, 0);
            acc0 = __builtin_amdgcn_mfma_f32_16x16x32_bf16(av_l, Bh0[kt], acc0, 0, 0, 0);
            acc1 = __builtin_amdgcn_mfma_f32_16x16x32_bf16(av_h, Bh1[kt], acc1, 0, 0, 0);
            acc1 = __builtin_amdgcn_mfma_f32_16x16x32_bf16(av_h, Bl1[kt], acc1, 0, 0, 0);
            acc1 = __builtin_amdgcn_mfma_f32_16x16x32_bf16(av_l, Bh1[kt], acc1, 0, 0, 0);
        }

        // ---- scatter gates (D: col=lane&15, row=(lane>>4)*4+reg) to [q][col][17] ----
        #pragma unroll
        for (int reg = 0; reg < 4; ++reg) {
            gateL[(wid * 32 + cidx) * 17      + kh * 4 + reg] = acc0[reg];
            gateL[(wid * 32 + 16 + cidx) * 17 + kh * 4 + reg] = acc1[reg];
        }
        __syncthreads();

        // ---- eltwise LSTM cell for (er, eu) and (er, eu+16) ----
        const float xv = xrow[t];
        float g0[4], g1[4];
        #pragma unroll
        for (int q = 0; q < 4; ++q) {
            g0[q] = gateL[(q * 32 + eu) * 17 + er]      + xv * wx0[q] + bb0[q];
            g1[q] = gateL[(q * 32 + 16 + eu) * 17 + er] + xv * wx1[q] + bb1[q];
        }
        cc0 = fmaf(sigmoidf_(g0[2] + 1.0f), cc0, sigmoidf_(g0[0]) * tanhf_(g0[1]));
        const float h0 = sigmoidf_(g0[3]) * tanhf_(cc0);
        cc1 = fmaf(sigmoidf_(g1[2] + 1.0f), cc1, sigmoidf_(g1[0]) * tanhf_(g1[1]));
        const float h1 = sigmoidf_(g1[3]) * tanhf_(cc1);

        // ---- pack own h-chunk (A-frag order) and store ----
        const float h0n = __shfl_xor(h0, 1, 64);
        const float h1n = __shfl_xor(h1, 1, 64);
        if ((eu & 1) == 0) {
            const int bufw  = (t + 1) & 1;
            const int basew = ((bufw * NGRP + g) * NSLC + s) * 512 + er * 16;
            const uint32_t hi0 = bf16rne(h0),  hi0n = bf16rne(h0n);
            const uint32_t hi1 = bf16rne(h1),  hi1n = bf16rne(h1n);
            const uint32_t lo0  = bf16rne(h0  - bf16tof(hi0));
            const uint32_t lo0n = bf16rne(h0n - bf16tof(hi0n));
            const uint32_t lo1  = bf16rne(h1  - bf16tof(hi1));
            const uint32_t lo1n = bf16rne(h1n - bf16tof(hi1n));
            const int D0 = eu >> 1, D1 = 8 + (eu >> 1);
            __hip_atomic_store(&hx[basew + D0], hi0 | (hi0n << 16),
                               __ATOMIC_RELAXED, __HIP_MEMORY_SCOPE_AGENT);
            __hip_atomic_store(&hx[basew + D1], hi1 | (hi1n << 16),
                               __ATOMIC_RELAXED, __HIP_MEMORY_SCOPE_AGENT);
            __hip_atomic_store(&hx[basew + 256 + D0], lo0 | (lo0n << 16),
                               __ATOMIC_RELAXED, __HIP_MEMORY_SCOPE_AGENT);
            __hip_atomic_store(&hx[basew + 256 + D1], lo1 | (lo1n << 16),
                               __ATOMIC_RELAXED, __HIP_MEMORY_SCOPE_AGENT);
        }
        // ---- per-wave: drain OWN stores (vmcnt is per-wave), lane0 tags ----
        asm volatile("s_waitcnt vmcnt(0)" ::: "memory");
        if (lane == 0) {
            __hip_atomic_store(&tags[g * 32 + s * 4 + wid], (uint32_t)(t + 1),
                               __ATOMIC_RELAXED, __HIP_MEMORY_SCOPE_AGENT);
        }
    }
}

// One block per batch row: dense = relu(h @ W_dense + b); logits = dense @ W_pred + b
__global__ __launch_bounds__(256, 1)
void head_kernel(const uint32_t* __restrict__ hx,
                 const float* __restrict__ W_dense,
                 const float* __restrict__ b_dense,
                 const float* __restrict__ W_pred,
                 const float* __restrict__ b_pred,
                 float* __restrict__ out) {
    __shared__ float hs[HID];
    __shared__ float ds[DNS];
    __shared__ float red[4];

    const int b = blockIdx.x;
    const int g = b >> 4, er = b & 15;
    const int tid = threadIdx.x;

    {   // reconstruct h = hi + lo from buf 0 chunk of (g, slice s)
        const int s  = tid >> 5;
        const int uu = tid & 31;
        const int base = (g * NSLC + s) * 512 + er * 16;
        const uint32_t dh = __hip_atomic_load(&hx[base + (uu >> 1)],
                                              __ATOMIC_RELAXED, __HIP_MEMORY_SCOPE_AGENT);
        const uint32_t dl = __hip_atomic_load(&hx[base + 256 + (uu >> 1)],
                                              __ATOMIC_RELAXED, __HIP_MEMORY_SCOPE_AGENT);
        const int sh = (uu & 1) * 16;
        hs[tid] = bf16tof((dh >> sh) & 0xFFFFu) + bf16tof((dl >> sh) & 0xFFFFu);
    }
    __syncthreads();

    for (int d = tid; d < DNS; d += 256) {
        float acc = b_dense[d];
        for (int k = 0; k < HID; k += 4) {
            float4 h4 = *reinterpret_cast<const float4*>(&hs[k]);
            acc = fmaf(h4.x, W_dense[(k + 0) * DNS + d], acc);
            acc = fmaf(h4.y, W_dense[(k + 1) * DNS + d], acc);
            acc = fmaf(h4.z, W_dense[(k + 2) * DNS + d], acc);
            acc = fmaf(h4.w, W_dense[(k + 3) * DNS + d], acc);
        }
        ds[d] = fmaxf(acc, 0.0f);
    }
    __syncthreads();

    const int wid = tid >> 6, lane = tid & 63;
    for (int c = 0; c < NCLS; ++c) {
        float p = 0.0f;
        for (int k = tid; k < DNS; k += 256) {
            p = fmaf(ds[k], W_pred[k * NCLS + c], p);
        }
        #pragma unroll
        for (int off = 32; off > 0; off >>= 1) {
            p += __shfl_down(p, off, 64);
        }
        if (lane == 0) red[wid] = p;
        __syncthreads();
        if (tid == 0) {
            out[b * NCLS + c] = red[0] + red[1] + red[2] + red[3] + b_pred[c];
        }
        __syncthreads();
    }
}

extern "C" void kernel_launch(void* const* d_in, const int* in_sizes, int n_in,
                              void* d_out, int out_size, void* d_ws, size_t ws_size,
                              hipStream_t stream) {
    const float* X       = (const float*)d_in[0];
    const float* W_lstm  = (const float*)d_in[1];
    const float* b_lstm  = (const float*)d_in[2];
    const float* W_dense = (const float*)d_in[3];
    const float* b_dense = (const float*)d_in[4];
    const float* W_pred  = (const float*)d_in[5];
    const float* b_pred  = (const float*)d_in[6];
    float* out = (float*)d_out;

    uint32_t* hx   = (uint32_t*)d_ws;                 // 131072 dwords = 512 KB
    uint32_t* tags = hx + 131072;                     // 16 * 32 dwords (128 B/group)

    hipMemsetAsync(hx, 0, NGRP * NSLC * 512 * sizeof(uint32_t), stream);   // h_0 = 0 (buf 0)
    hipMemsetAsync(tags, 0, NGRP * 32 * sizeof(uint32_t), stream);

    lstm_mfma<<<NGRP * NSLC, 256, 0, stream>>>(X, W_lstm, b_lstm, hx, tags);
    head_kernel<<<BATCH, 256, 0, stream>>>(hx, W_dense, b_dense, W_pred, b_pred, out);
}

// Round 18
// 2266.908 us; speedup vs baseline: 1.0226x; 1.0226x over previous
//
#include <hip/hip_runtime.h>
#include <stdint.h>

#define TSEQ  784
#define BATCH 256
#define HID   256
#define DNS   1024
#define NCLS  10
#define NGRP  16   // groups (16 batch rows each)
#define NSLC  8    // slices (32 units x 4 gates = 128 gate-cols each)

typedef __attribute__((ext_vector_type(8))) short bf16x8_t;
typedef __attribute__((ext_vector_type(4))) float f32x4_t;

__device__ __forceinline__ float sigmoidf_(float x) { return 1.0f / (1.0f + __expf(-x)); }
__device__ __forceinline__ float tanhf_(float x) {
    float ax = fabsf(x);
    float e  = __expf(2.0f * ax);
    float r  = 1.0f - 2.0f / (e + 1.0f);
    return copysignf(r, x);
}
__device__ __forceinline__ uint32_t bf16rne(float f) {
    uint32_t u = __float_as_uint(f);
    return (u + 0x7FFFu + ((u >> 16) & 1u)) >> 16;
}
__device__ __forceinline__ float bf16tof(uint32_t h) { return __uint_as_float(h << 16); }

// 4x4 butterfly transpose across the 4 lanes {cidx>>2 = 0..3} (lane stride 4).
// In: M[r] = value(gate=p, rowlow=r) at lane-position p. Out: T[g] = value(gate=g, rowlow=p).
__device__ __forceinline__ f32x4_t xpose44(f32x4_t M, int p) {
    const bool pb1 = (p & 2) != 0;
    float s0 = pb1 ? M[0] : M[2];
    float s1 = pb1 ? M[1] : M[3];
    float r0 = __shfl_xor(s0, 8, 64);
    float r1 = __shfl_xor(s1, 8, 64);
    f32x4_t N;
    N[0] = pb1 ? r0 : M[0];
    N[1] = pb1 ? r1 : M[1];
    N[2] = pb1 ? M[2] : r0;
    N[3] = pb1 ? M[3] : r1;
    const bool pb0 = (p & 1) != 0;
    s0 = pb0 ? N[0] : N[1];
    s1 = pb0 ? N[2] : N[3];
    r0 = __shfl_xor(s0, 4, 64);
    r1 = __shfl_xor(s1, 4, 64);
    f32x4_t T;
    T[0] = pb0 ? r0 : N[0];
    T[1] = pb0 ? N[1] : r0;
    T[2] = pb0 ? r1 : N[2];
    T[3] = pb0 ? N[3] : r1;
    return T;
}

// 128 blocks = 16 groups x 8 slices, 256 threads (4 waves). r15 protocol
// (best: 2127 us) with the gate-LDS exchange DELETED: WtU n-tiles repacked as
// {4 units x 4 gates}, so each wave owns 8 units x all gates; a 2-stage
// shfl_xor 4x4 transpose gives every lane all 4 gates of its cell in
// registers. gateL gone, scatter gone, one barrier gone (3/step).
__global__ __launch_bounds__(256, 1)
void lstm_mfma(const float* __restrict__ X,
               const float* __restrict__ W_lstm,
               const float* __restrict__ b_lstm,
               uint32_t* __restrict__ hx,      // 2 bufs * 16 g * 8 s * 512 dwords
               uint32_t* __restrict__ tags)    // 128 monotonic tags
{
    __shared__ uint32_t WtU[32768];           // 128 KB weights bf16 hi/lo (frag source)
    __shared__ uint32_t hA[4096];             // 16 KB h_t (hi/lo), A-frag order, swizzled

    const int tid  = threadIdx.x;
    const int lane = tid & 63;
    const int wid  = tid >> 6;    // wave owns n-tiles {2wid, 2wid+1} = units 8wid..8wid+7
    const int cidx = lane & 15;   // B col / A row within tile
    const int kh   = lane >> 4;   // 0..3 k-subgroup

    const int bid = blockIdx.x;
    const int s   = bid >> 4;     // slice 0..7
    const int g   = bid & 15;     // group 0..15

    // ---- one-time: stage Wh slice into LDS, bf16 hi/lo, chunk-XOR-swizzled.
    // NEW packing: n-tile n, col c -> gate = c>>2, unit = n*4 + (c&3).
    for (int idx = tid; idx < 8 * 16 * 128; idx += 256) {
        const int n  = idx >> 11;          // n-tile 0..7
        const int c  = (idx >> 7) & 15;    // col within tile
        const int dw = idx & 127;          // k-pair index
        const int k0 = dw * 2;
        const int col = (c >> 2) * 256 + s * 32 + n * 4 + (c & 3);
        const float w0 = W_lstm[(1 + k0) * 1024 + col];
        const float w1 = W_lstm[(2 + k0) * 1024 + col];
        const uint32_t h0 = bf16rne(w0), h1 = bf16rne(w1);
        const uint32_t l0 = bf16rne(w0 - bf16tof(h0));
        const uint32_t l1 = bf16rne(w1 - bf16tof(h1));
        const int kc = dw >> 2, rem = dw & 3;
        const int dwp = ((kc ^ (c & 7)) << 2) | rem;
        const int o = (n * 16 + c) * 128 + dwp;
        WtU[o]         = h0 | (h1 << 16);
        WtU[16384 + o] = l0 | (l1 << 16);
    }

    // ---- per-lane cell assignment (t-invariant) ----
    const int p     = cidx >> 2;            // lane position in 4-lane transpose group
    const int row   = kh * 4 + p;           // batch row within group
    const int unitA = 8 * wid + (cidx & 3); // acc0's unit
    const int unitB = unitA + 4;            // acc1's unit
    float wxA[4], wxB[4], bbA[4], bbB[4];
    #pragma unroll
    for (int q = 0; q < 4; ++q) {
        wxA[q] = W_lstm[q * 256 + s * 32 + unitA];
        wxB[q] = W_lstm[q * 256 + s * 32 + unitB];
        bbA[q] = b_lstm[q * 256 + s * 32 + unitA];
        bbB[q] = b_lstm[q * 256 + s * 32 + unitB];
    }
    const float* xrowp = X + (g * 16 + row) * TSEQ;
    float ccA = 0.0f, ccB = 0.0f;

    const int key = (cidx + (cidx >> 2)) & 3;   // hA read swizzle key
    const int kq  = (kh ^ key) << 2;

    __syncthreads();

    // ---- hoist this wave's B-fragments into registers (32 x bf16x8) ----
    bf16x8_t Bh0[8], Bl0[8], Bh1[8], Bl1[8];
    #pragma unroll
    for (int kt = 0; kt < 8; ++kt) {
        const int kc  = kt * 4 + kh;
        const int ob0 = ((wid * 2) * 16 + cidx) * 128 + ((kc ^ (cidx & 7)) << 2);
        const int ob1 = ((wid * 2 + 1) * 16 + cidx) * 128 + ((kc ^ (cidx & 7)) << 2);
        Bh0[kt] = *reinterpret_cast<const bf16x8_t*>(&WtU[ob0]);
        Bl0[kt] = *reinterpret_cast<const bf16x8_t*>(&WtU[16384 + ob0]);
        Bh1[kt] = *reinterpret_cast<const bf16x8_t*>(&WtU[ob1]);
        Bl1[kt] = *reinterpret_cast<const bf16x8_t*>(&WtU[16384 + ob1]);
    }

    for (int t = 0; t < TSEQ; ++t) {
        // PIN: loop-carried residency hint for the B-fragments (r15 win: kept).
        #pragma unroll
        for (int kt = 0; kt < 8; kt += 4) {
            asm volatile("" : "+v"(Bh0[kt]), "+v"(Bh0[kt+1]), "+v"(Bh0[kt+2]), "+v"(Bh0[kt+3]),
                              "+v"(Bl0[kt]), "+v"(Bl0[kt+1]), "+v"(Bl0[kt+2]), "+v"(Bl0[kt+3]));
            asm volatile("" : "+v"(Bh1[kt]), "+v"(Bh1[kt+1]), "+v"(Bh1[kt+2]), "+v"(Bh1[kt+3]),
                              "+v"(Bl1[kt]), "+v"(Bl1[kt+1]), "+v"(Bl1[kt+2]), "+v"(Bl1[kt+3]));
        }

        // ---- wave 0 polls all 8 producer tags >= t (r15 exact) ----
        if (t > 0 && wid == 0) {
            const uint32_t tt = (uint32_t)t;
            int guard = 1 << 22;
            bool ok;
            do {
                uint32_t v = __hip_atomic_load(&tags[g * 8 + (lane & 7)],
                                               __ATOMIC_RELAXED, __HIP_MEMORY_SCOPE_AGENT);
                ok = __all(v >= tt);
            } while (!ok && --guard);
        }
        __syncthreads();   // join + fence: stage loads cannot hoist above poll

        // ---- stage h_t (hi+lo, all 8 chunks = 16 KB) into LDS, coalesced u64 ----
        {
            const int bufr = t & 1;
            const unsigned long long* src =
                (const unsigned long long*)hx + (size_t)(bufr * NGRP + g) * 2048;
            unsigned long long v[8];
            #pragma unroll
            for (int j = 0; j < 8; ++j) {
                v[j] = __hip_atomic_load(&src[j * 256 + tid],
                                         __ATOMIC_RELAXED, __HIP_MEMORY_SCOPE_AGENT);
            }
            #pragma unroll
            for (int j = 0; j < 8; ++j) {
                const int m   = j * 256 + tid;      // u64 index; dword n = 2m
                const int kt  = m >> 8;
                const int lvl = (m >> 7) & 1;
                const int ci  = (m & 127) >> 3;
                const int ko  = (m & 7) * 2;        // even koff
                const int khj = ko >> 2, dp = ko & 3;
                const int kyj = (ci + (ci >> 2)) & 3;
                const int dst = kt * 512 + lvl * 256 + ci * 16 + ((khj ^ kyj) << 2) + dp;
                *(unsigned long long*)&hA[dst] = v[j];
            }
        }
        __syncthreads();

        // ---- GEMM: 3-term split over 8 k-tiles, B from registers/pin ----
        f32x4_t acc0 = {0.f, 0.f, 0.f, 0.f}, acc1 = acc0;
        #pragma unroll
        for (int kt = 0; kt < 8; ++kt) {
            bf16x8_t av_h = *reinterpret_cast<const bf16x8_t*>(&hA[kt * 512 + cidx * 16 + kq]);
            bf16x8_t av_l = *reinterpret_cast<const bf16x8_t*>(&hA[kt * 512 + 256 + cidx * 16 + kq]);
            acc0 = __builtin_amdgcn_mfma_f32_16x16x32_bf16(av_h, Bh0[kt], acc0, 0, 0, 0);
            acc0 = __builtin_amdgcn_mfma_f32_16x16x32_bf16(av_h, Bl0[kt], acc0, 0, 0, 0);
            acc0 = __builtin_amdgcn_mfma_f32_16x16x32_bf16(av_l, Bh0[kt], acc0, 0, 0, 0);
            acc1 = __builtin_amdgcn_mfma_f32_16x16x32_bf16(av_h, Bh1[kt], acc1, 0, 0, 0);
            acc1 = __builtin_amdgcn_mfma_f32_16x16x32_bf16(av_h, Bl1[kt], acc1, 0, 0, 0);
            acc1 = __builtin_amdgcn_mfma_f32_16x16x32_bf16(av_l, Bh1[kt], acc1, 0, 0, 0);
        }

        // ---- in-register gate transpose: lane gets all 4 gates of its cell ----
        f32x4_t TA = xpose44(acc0, p);   // TA[g] = gate g of (row, unitA)
        f32x4_t TB = xpose44(acc1, p);   // TB[g] = gate g of (row, unitB)

        // ---- eltwise LSTM cells (row, unitA) and (row, unitB) ----
        const float xv = xrowp[t];
        float gA[4], gB[4];
        #pragma unroll
        for (int q = 0; q < 4; ++q) {
            gA[q] = TA[q] + xv * wxA[q] + bbA[q];
            gB[q] = TB[q] + xv * wxB[q] + bbB[q];
        }
        ccA = fmaf(sigmoidf_(gA[2] + 1.0f), ccA, sigmoidf_(gA[0]) * tanhf_(gA[1]));
        const float h0 = sigmoidf_(gA[3]) * tanhf_(ccA);
        ccB = fmaf(sigmoidf_(gB[2] + 1.0f), ccB, sigmoidf_(gB[0]) * tanhf_(gB[1]));
        const float h1 = sigmoidf_(gB[3]) * tanhf_(ccB);

        // ---- pack own h-chunk (A-frag order): partner unit^1 = lane^1 ----
        const float h0n = __shfl_xor(h0, 1, 64);
        const float h1n = __shfl_xor(h1, 1, 64);
        if ((cidx & 1) == 0) {
            const int bufw  = (t + 1) & 1;
            const int basew = ((bufw * NGRP + g) * NSLC + s) * 512 + row * 16;
            const uint32_t hi0 = bf16rne(h0),  hi0n = bf16rne(h0n);
            const uint32_t hi1 = bf16rne(h1),  hi1n = bf16rne(h1n);
            const uint32_t lo0  = bf16rne(h0  - bf16tof(hi0));
            const uint32_t lo0n = bf16rne(h0n - bf16tof(hi0n));
            const uint32_t lo1  = bf16rne(h1  - bf16tof(hi1));
            const uint32_t lo1n = bf16rne(h1n - bf16tof(hi1n));
            const int DA = unitA >> 1;   // pair dword for (unitA, unitA+1)
            const int DB = unitB >> 1;
            __hip_atomic_store(&hx[basew + DA], hi0 | (hi0n << 16),
                               __ATOMIC_RELAXED, __HIP_MEMORY_SCOPE_AGENT);
            __hip_atomic_store(&hx[basew + DB], hi1 | (hi1n << 16),
                               __ATOMIC_RELAXED, __HIP_MEMORY_SCOPE_AGENT);
            __hip_atomic_store(&hx[basew + 256 + DA], lo0 | (lo0n << 16),
                               __ATOMIC_RELAXED, __HIP_MEMORY_SCOPE_AGENT);
            __hip_atomic_store(&hx[basew + 256 + DB], lo1 | (lo1n << 16),
                               __ATOMIC_RELAXED, __HIP_MEMORY_SCOPE_AGENT);
        }
        __syncthreads();   // drains vmcnt(0): chunk stores at coherent point
        if (tid == 0) {
            __hip_atomic_store(&tags[g * 8 + s], (uint32_t)(t + 1),
                               __ATOMIC_RELAXED, __HIP_MEMORY_SCOPE_AGENT);
        }
    }
}

// One block per batch row: dense = relu(h @ W_dense + b); logits = dense @ W_pred + b
__global__ __launch_bounds__(256, 1)
void head_kernel(const uint32_t* __restrict__ hx,
                 const float* __restrict__ W_dense,
                 const float* __restrict__ b_dense,
                 const float* __restrict__ W_pred,
                 const float* __restrict__ b_pred,
                 float* __restrict__ out) {
    __shared__ float hs[HID];
    __shared__ float ds[DNS];
    __shared__ float red[4];

    const int b = blockIdx.x;
    const int g = b >> 4, er = b & 15;
    const int tid = threadIdx.x;

    {   // reconstruct h = hi + lo from buf 0 chunk of (g, slice s)
        const int s  = tid >> 5;
        const int uu = tid & 31;
        const int base = (g * NSLC + s) * 512 + er * 16;
        const uint32_t dh = __hip_atomic_load(&hx[base + (uu >> 1)],
                                              __ATOMIC_RELAXED, __HIP_MEMORY_SCOPE_AGENT);
        const uint32_t dl = __hip_atomic_load(&hx[base + 256 + (uu >> 1)],
                                              __ATOMIC_RELAXED, __HIP_MEMORY_SCOPE_AGENT);
        const int sh = (uu & 1) * 16;
        hs[tid] = bf16tof((dh >> sh) & 0xFFFFu) + bf16tof((dl >> sh) & 0xFFFFu);
    }
    __syncthreads();

    for (int d = tid; d < DNS; d += 256) {
        float acc = b_dense[d];
        for (int k = 0; k < HID; k += 4) {
            float4 h4 = *reinterpret_cast<const float4*>(&hs[k]);
            acc = fmaf(h4.x, W_dense[(k + 0) * DNS + d], acc);
            acc = fmaf(h4.y, W_dense[(k + 1) * DNS + d], acc);
            acc = fmaf(h4.z, W_dense[(k + 2) * DNS + d], acc);
            acc = fmaf(h4.w, W_dense[(k + 3) * DNS + d], acc);
        }
        ds[d] = fmaxf(acc, 0.0f);
    }
    __syncthreads();

    const int wid = tid >> 6, lane = tid & 63;
    for (int c = 0; c < NCLS; ++c) {
        float p = 0.0f;
        for (int k = tid; k < DNS; k += 256) {
            p = fmaf(ds[k], W_pred[k * NCLS + c], p);
        }
        #pragma unroll
        for (int off = 32; off > 0; off >>= 1) {
            p += __shfl_down(p, off, 64);
        }
        if (lane == 0) red[wid] = p;
        __syncthreads();
        if (tid == 0) {
            out[b * NCLS + c] = red[0] + red[1] + red[2] + red[3] + b_pred[c];
        }
        __syncthreads();
    }
}

extern "C" void kernel_launch(void* const* d_in, const int* in_sizes, int n_in,
                              void* d_out, int out_size, void* d_ws, size_t ws_size,
                              hipStream_t stream) {
    const float* X       = (const float*)d_in[0];
    const float* W_lstm  = (const float*)d_in[1];
    const float* b_lstm  = (const float*)d_in[2];
    const float* W_dense = (const float*)d_in[3];
    const float* b_dense = (const float*)d_in[4];
    const float* W_pred  = (const float*)d_in[5];
    const float* b_pred  = (const float*)d_in[6];
    float* out = (float*)d_out;

    uint32_t* hx   = (uint32_t*)d_ws;                 // 131072 dwords = 512 KB
    uint32_t* tags = hx + 131072;                     // 128 dwords

    hipMemsetAsync(hx, 0, NGRP * NSLC * 512 * sizeof(uint32_t), stream);   // h_0 = 0 (buf 0)
    hipMemsetAsync(tags, 0, NGRP * NSLC * sizeof(uint32_t), stream);

    lstm_mfma<<<NGRP * NSLC, 256, 0, stream>>>(X, W_lstm, b_lstm, hx, tags);
    head_kernel<<<BATCH, 256, 0, stream>>>(hx, W_dense, b_dense, W_pred, b_pred, out);
}

// Round 19
// 2125.763 us; speedup vs baseline: 1.0905x; 1.0664x over previous
//
#include <hip/hip_runtime.h>
#include <stdint.h>

#define TSEQ  784
#define BATCH 256
#define HID   256
#define DNS   1024
#define NCLS  10
#define NGRP  16   // groups (16 batch rows each)
#define NSLC  8    // slices (32 units x 4 gates = 128 gate-cols each)

typedef __attribute__((ext_vector_type(8))) short bf16x8_t;
typedef __attribute__((ext_vector_type(4))) float f32x4_t;

__device__ __forceinline__ float sigmoidf_(float x) { return 1.0f / (1.0f + __expf(-x)); }
__device__ __forceinline__ float tanhf_(float x) {
    float ax = fabsf(x);
    float e  = __expf(2.0f * ax);
    float r  = 1.0f - 2.0f / (e + 1.0f);
    return copysignf(r, x);
}
__device__ __forceinline__ uint32_t bf16rne(float f) {
    uint32_t u = __float_as_uint(f);
    return (u + 0x7FFFu + ((u >> 16) & 1u)) >> 16;
}
__device__ __forceinline__ float bf16tof(uint32_t h) { return __uint_as_float(h << 16); }

// 128 blocks = 16 groups x 8 slices, 256 threads (4 waves). EXACT round-8
// exchange protocol (11 experiments bracket it as the optimum) + round-15
// B-fragment hoist/pin (best measured: 2127 us).
__global__ __launch_bounds__(256, 1)
void lstm_mfma(const float* __restrict__ X,
               const float* __restrict__ W_lstm,
               const float* __restrict__ b_lstm,
               uint32_t* __restrict__ hx,      // 2 bufs * 16 g * 8 s * 512 dwords
               uint32_t* __restrict__ tags)    // 128 monotonic tags
{
    __shared__ uint32_t WtU[32768];           // 128 KB weights bf16 hi/lo (frag source)
    __shared__ uint32_t hA[4096];             // 16 KB h_t (hi/lo), A-frag order, swizzled
    __shared__ float    gateL[4 * 32 * 17];   // 8.5 KB gates [q][col][row+pad]

    const int tid  = threadIdx.x;
    const int lane = tid & 63;
    const int wid  = tid >> 6;    // 0..3 == gate q owned by this wave
    const int cidx = lane & 15;   // B col / A row within tile
    const int kh   = lane >> 4;   // 0..3 k-subgroup

    const int bid = blockIdx.x;
    const int s   = bid >> 4;     // slice 0..7
    const int g   = bid & 15;     // group 0..15

    // ---- one-time: stage Wh slice into LDS as bf16 hi/lo, chunk-XOR-swizzled ----
    for (int idx = tid; idx < 8 * 16 * 128; idx += 256) {
        const int n  = idx >> 11;          // n-tile 0..7
        const int c  = (idx >> 7) & 15;    // col within tile
        const int dw = idx & 127;          // k-pair index
        const int k0 = dw * 2;
        const int col = (n >> 1) * 256 + s * 32 + (n & 1) * 16 + c;
        const float w0 = W_lstm[(1 + k0) * 1024 + col];
        const float w1 = W_lstm[(2 + k0) * 1024 + col];
        const uint32_t h0 = bf16rne(w0), h1 = bf16rne(w1);
        const uint32_t l0 = bf16rne(w0 - bf16tof(h0));
        const uint32_t l1 = bf16rne(w1 - bf16tof(h1));
        const int kc = dw >> 2, rem = dw & 3;
        const int dwp = ((kc ^ (c & 7)) << 2) | rem;
        const int o = (n * 16 + c) * 128 + dwp;
        WtU[o]         = h0 | (h1 << 16);
        WtU[16384 + o] = l0 | (l1 << 16);
    }

    // eltwise mapping: thread -> (row er, unit eu); cells (er,eu),(er,eu+16)
    const int er = tid >> 4;
    const int eu = tid & 15;
    float wx0[4], wx1[4], bb0[4], bb1[4];
    #pragma unroll
    for (int q = 0; q < 4; ++q) {
        const int c0 = q * 256 + s * 32 + eu;
        wx0[q] = W_lstm[c0];      wx1[q] = W_lstm[c0 + 16];
        bb0[q] = b_lstm[c0];      bb1[q] = b_lstm[c0 + 16];
    }
    const float* xrow = X + (g * 16 + er) * TSEQ;
    float cc0 = 0.0f, cc1 = 0.0f;

    const int key = (cidx + (cidx >> 2)) & 3;   // hA read swizzle key
    const int kq  = (kh ^ key) << 2;

    __syncthreads();

    // ---- hoist this wave's B-fragments into registers (32 x bf16x8) ----
    bf16x8_t Bh0[8], Bl0[8], Bh1[8], Bl1[8];
    #pragma unroll
    for (int kt = 0; kt < 8; ++kt) {
        const int kc  = kt * 4 + kh;
        const int ob0 = ((wid * 2) * 16 + cidx) * 128 + ((kc ^ (cidx & 7)) << 2);
        const int ob1 = ((wid * 2 + 1) * 16 + cidx) * 128 + ((kc ^ (cidx & 7)) << 2);
        Bh0[kt] = *reinterpret_cast<const bf16x8_t*>(&WtU[ob0]);
        Bl0[kt] = *reinterpret_cast<const bf16x8_t*>(&WtU[16384 + ob0]);
        Bh1[kt] = *reinterpret_cast<const bf16x8_t*>(&WtU[ob1]);
        Bl1[kt] = *reinterpret_cast<const bf16x8_t*>(&WtU[16384 + ob1]);
    }

    for (int t = 0; t < TSEQ; ++t) {
        // PIN: loop-carried residency hint for the B-fragments (r15 win: kept).
        #pragma unroll
        for (int kt = 0; kt < 8; kt += 4) {
            asm volatile("" : "+v"(Bh0[kt]), "+v"(Bh0[kt+1]), "+v"(Bh0[kt+2]), "+v"(Bh0[kt+3]),
                              "+v"(Bl0[kt]), "+v"(Bl0[kt+1]), "+v"(Bl0[kt+2]), "+v"(Bl0[kt+3]));
            asm volatile("" : "+v"(Bh1[kt]), "+v"(Bh1[kt+1]), "+v"(Bh1[kt+2]), "+v"(Bh1[kt+3]),
                              "+v"(Bl1[kt]), "+v"(Bl1[kt+1]), "+v"(Bl1[kt+2]), "+v"(Bl1[kt+3]));
        }

        // ---- wave 0 polls all 8 producer tags >= t ----
        if (t > 0 && wid == 0) {
            const uint32_t tt = (uint32_t)t;
            int guard = 1 << 22;
            bool ok;
            do {
                uint32_t v = __hip_atomic_load(&tags[g * 8 + (lane & 7)],
                                               __ATOMIC_RELAXED, __HIP_MEMORY_SCOPE_AGENT);
                ok = __all(v >= tt);
            } while (!ok && --guard);
        }
        __syncthreads();   // join + fence: stage loads cannot hoist above poll

        // ---- stage h_t (hi+lo, all 8 chunks = 16 KB) into LDS, coalesced u64 ----
        {
            const int bufr = t & 1;
            const unsigned long long* src =
                (const unsigned long long*)hx + (size_t)(bufr * NGRP + g) * 2048;
            unsigned long long v[8];
            #pragma unroll
            for (int j = 0; j < 8; ++j) {
                v[j] = __hip_atomic_load(&src[j * 256 + tid],
                                         __ATOMIC_RELAXED, __HIP_MEMORY_SCOPE_AGENT);
            }
            #pragma unroll
            for (int j = 0; j < 8; ++j) {
                const int m   = j * 256 + tid;      // u64 index; dword n = 2m
                const int kt  = m >> 8;
                const int lvl = (m >> 7) & 1;
                const int ci  = (m & 127) >> 3;
                const int ko  = (m & 7) * 2;        // even koff
                const int khj = ko >> 2, dp = ko & 3;
                const int kyj = (ci + (ci >> 2)) & 3;
                const int dst = kt * 512 + lvl * 256 + ci * 16 + ((khj ^ kyj) << 2) + dp;
                *(unsigned long long*)&hA[dst] = v[j];
            }
        }
        __syncthreads();

        // ---- GEMM: 3-term split over 8 k-tiles, B from registers/pin ----
        f32x4_t acc0 = {0.f, 0.f, 0.f, 0.f}, acc1 = acc0;
        #pragma unroll
        for (int kt = 0; kt < 8; ++kt) {
            bf16x8_t av_h = *reinterpret_cast<const bf16x8_t*>(&hA[kt * 512 + cidx * 16 + kq]);
            bf16x8_t av_l = *reinterpret_cast<const bf16x8_t*>(&hA[kt * 512 + 256 + cidx * 16 + kq]);
            acc0 = __builtin_amdgcn_mfma_f32_16x16x32_bf16(av_h, Bh0[kt], acc0, 0, 0, 0);
            acc0 = __builtin_amdgcn_mfma_f32_16x16x32_bf16(av_h, Bl0[kt], acc0, 0, 0, 0);
            acc0 = __builtin_amdgcn_mfma_f32_16x16x32_bf16(av_l, Bh0[kt], acc0, 0, 0, 0);
            acc1 = __builtin_amdgcn_mfma_f32_16x16x32_bf16(av_h, Bh1[kt], acc1, 0, 0, 0);
            acc1 = __builtin_amdgcn_mfma_f32_16x16x32_bf16(av_h, Bl1[kt], acc1, 0, 0, 0);
            acc1 = __builtin_amdgcn_mfma_f32_16x16x32_bf16(av_l, Bh1[kt], acc1, 0, 0, 0);
        }

        // ---- scatter gates (D: col=lane&15, row=(lane>>4)*4+reg) to [q][col][17] ----
        #pragma unroll
        for (int reg = 0; reg < 4; ++reg) {
            gateL[(wid * 32 + cidx) * 17      + kh * 4 + reg] = acc0[reg];
            gateL[(wid * 32 + 16 + cidx) * 17 + kh * 4 + reg] = acc1[reg];
        }
        __syncthreads();

        // ---- eltwise LSTM cell for (er, eu) and (er, eu+16) ----
        const float xv = xrow[t];
        float g0[4], g1[4];
        #pragma unroll
        for (int q = 0; q < 4; ++q) {
            g0[q] = gateL[(q * 32 + eu) * 17 + er]      + xv * wx0[q] + bb0[q];
            g1[q] = gateL[(q * 32 + 16 + eu) * 17 + er] + xv * wx1[q] + bb1[q];
        }
        cc0 = fmaf(sigmoidf_(g0[2] + 1.0f), cc0, sigmoidf_(g0[0]) * tanhf_(g0[1]));
        const float h0 = sigmoidf_(g0[3]) * tanhf_(cc0);
        cc1 = fmaf(sigmoidf_(g1[2] + 1.0f), cc1, sigmoidf_(g1[0]) * tanhf_(g1[1]));
        const float h1 = sigmoidf_(g1[3]) * tanhf_(cc1);

        // ---- pack own h-chunk (A-frag order) and store ----
        const float h0n = __shfl_xor(h0, 1, 64);
        const float h1n = __shfl_xor(h1, 1, 64);
        if ((eu & 1) == 0) {
            const int bufw  = (t + 1) & 1;
            const int basew = ((bufw * NGRP + g) * NSLC + s) * 512 + er * 16;
            const uint32_t hi0 = bf16rne(h0),  hi0n = bf16rne(h0n);
            const uint32_t hi1 = bf16rne(h1),  hi1n = bf16rne(h1n);
            const uint32_t lo0  = bf16rne(h0  - bf16tof(hi0));
            const uint32_t lo0n = bf16rne(h0n - bf16tof(hi0n));
            const uint32_t lo1  = bf16rne(h1  - bf16tof(hi1));
            const uint32_t lo1n = bf16rne(h1n - bf16tof(hi1n));
            const int D0 = eu >> 1, D1 = 8 + (eu >> 1);
            __hip_atomic_store(&hx[basew + D0], hi0 | (hi0n << 16),
                               __ATOMIC_RELAXED, __HIP_MEMORY_SCOPE_AGENT);
            __hip_atomic_store(&hx[basew + D1], hi1 | (hi1n << 16),
                               __ATOMIC_RELAXED, __HIP_MEMORY_SCOPE_AGENT);
            __hip_atomic_store(&hx[basew + 256 + D0], lo0 | (lo0n << 16),
                               __ATOMIC_RELAXED, __HIP_MEMORY_SCOPE_AGENT);
            __hip_atomic_store(&hx[basew + 256 + D1], lo1 | (lo1n << 16),
                               __ATOMIC_RELAXED, __HIP_MEMORY_SCOPE_AGENT);
        }
        __syncthreads();   // drains vmcnt(0): chunk stores at coherent point
        if (tid == 0) {
            __hip_atomic_store(&tags[g * 8 + s], (uint32_t)(t + 1),
                               __ATOMIC_RELAXED, __HIP_MEMORY_SCOPE_AGENT);
        }
    }
}

// One block per batch row: dense = relu(h @ W_dense + b); logits = dense @ W_pred + b
__global__ __launch_bounds__(256, 1)
void head_kernel(const uint32_t* __restrict__ hx,
                 const float* __restrict__ W_dense,
                 const float* __restrict__ b_dense,
                 const float* __restrict__ W_pred,
                 const float* __restrict__ b_pred,
                 float* __restrict__ out) {
    __shared__ float hs[HID];
    __shared__ float ds[DNS];
    __shared__ float red[4];

    const int b = blockIdx.x;
    const int g = b >> 4, er = b & 15;
    const int tid = threadIdx.x;

    {   // reconstruct h = hi + lo from buf 0 chunk of (g, slice s)
        const int s  = tid >> 5;
        const int uu = tid & 31;
        const int base = (g * NSLC + s) * 512 + er * 16;
        const uint32_t dh = __hip_atomic_load(&hx[base + (uu >> 1)],
                                              __ATOMIC_RELAXED, __HIP_MEMORY_SCOPE_AGENT);
        const uint32_t dl = __hip_atomic_load(&hx[base + 256 + (uu >> 1)],
                                              __ATOMIC_RELAXED, __HIP_MEMORY_SCOPE_AGENT);
        const int sh = (uu & 1) * 16;
        hs[tid] = bf16tof((dh >> sh) & 0xFFFFu) + bf16tof((dl >> sh) & 0xFFFFu);
    }
    __syncthreads();

    for (int d = tid; d < DNS; d += 256) {
        float acc = b_dense[d];
        for (int k = 0; k < HID; k += 4) {
            float4 h4 = *reinterpret_cast<const float4*>(&hs[k]);
            acc = fmaf(h4.x, W_dense[(k + 0) * DNS + d], acc);
            acc = fmaf(h4.y, W_dense[(k + 1) * DNS + d], acc);
            acc = fmaf(h4.z, W_dense[(k + 2) * DNS + d], acc);
            acc = fmaf(h4.w, W_dense[(k + 3) * DNS + d], acc);
        }
        ds[d] = fmaxf(acc, 0.0f);
    }
    __syncthreads();

    const int wid = tid >> 6, lane = tid & 63;
    for (int c = 0; c < NCLS; ++c) {
        float p = 0.0f;
        for (int k = tid; k < DNS; k += 256) {
            p = fmaf(ds[k], W_pred[k * NCLS + c], p);
        }
        #pragma unroll
        for (int off = 32; off > 0; off >>= 1) {
            p += __shfl_down(p, off, 64);
        }
        if (lane == 0) red[wid] = p;
        __syncthreads();
        if (tid == 0) {
            out[b * NCLS + c] = red[0] + red[1] + red[2] + red[3] + b_pred[c];
        }
        __syncthreads();
    }
}

extern "C" void kernel_launch(void* const* d_in, const int* in_sizes, int n_in,
                              void* d_out, int out_size, void* d_ws, size_t ws_size,
                              hipStream_t stream) {
    const float* X       = (const float*)d_in[0];
    const float* W_lstm  = (const float*)d_in[1];
    const float* b_lstm  = (const float*)d_in[2];
    const float* W_dense = (const float*)d_in[3];
    const float* b_dense = (const float*)d_in[4];
    const float* W_pred  = (const float*)d_in[5];
    const float* b_pred  = (const float*)d_in[6];
    float* out = (float*)d_out;

    uint32_t* hx   = (uint32_t*)d_ws;                 // 131072 dwords = 512 KB
    uint32_t* tags = hx + 131072;                     // 128 dwords

    hipMemsetAsync(hx, 0, NGRP * NSLC * 512 * sizeof(uint32_t), stream);   // h_0 = 0 (buf 0)
    hipMemsetAsync(tags, 0, NGRP * NSLC * sizeof(uint32_t), stream);

    lstm_mfma<<<NGRP * NSLC, 256, 0, stream>>>(X, W_lstm, b_lstm, hx, tags);
    head_kernel<<<BATCH, 256, 0, stream>>>(hx, W_dense, b_dense, W_pred, b_pred, out);
}